// Round 1
// baseline (1504.718 us; speedup 1.0000x reference)
//
#include <hip/hip_runtime.h>
#include <hip/hip_bf16.h>

// B=2, L=16, H=64, W=64, C=256.  n = B*L = 32, HW = 4096.
// ws layout (bytes):
//   [0, 64Mi)            : Q bf16 [n][c][s]   (later reused for V^T [n'][s'][d])
//   [64Mi, 128Mi)        : K bf16 [n][d][s_k] (s_k = w*64+h, reference's W/H-swap)
//   [128Mi, +8Mi)        : attn logits fp32 [n][c][d]
//   [136Mi+..., +4Mi)    : attn probs bf16 [n][c][d]
//   [+384Ki]             : Wq/Wk/Wv as bf16
// Total ~147 MB.

typedef short short8 __attribute__((ext_vector_type(8)));
typedef float f32x4 __attribute__((ext_vector_type(4)));

static __device__ __forceinline__ unsigned short f2bf(float f) {
  union { __hip_bfloat16 h; unsigned short u; } cv;
  cv.h = __float2bfloat16(f);
  return cv.u;
}

__global__ __launch_bounds__(256) void k_convert_w(const float* __restrict__ wq,
                                                   const float* __restrict__ wk,
                                                   const float* __restrict__ wv,
                                                   unsigned short* __restrict__ o) {
  int i = blockIdx.x * 256 + threadIdx.x;
  const float* s = (i < 65536) ? wq : (i < 131072 ? wk : wv);
  o[i] = f2bf(s[i & 65535]);
}

// Pointwise conv GEMM: rows = 131072 spatial positions, K=256 in-ch, N=256 out-ch.
// MODE 0: Q -> dst[n][o][s],  s = h*64+w
// MODE 1: K -> dst[n][o][w*64+h]
// MODE 2: V -> dst[n'][s][c']  (buggy-reshape permutation, stored s-major = V^T)
template <int MODE>
__global__ __launch_bounds__(256) void k_qkv(const float* __restrict__ src,
                                             const unsigned short* __restrict__ w,
                                             const float* __restrict__ bias,
                                             unsigned short* __restrict__ dst) {
  __shared__ unsigned short lds[64 * 264];  // 64 rows x 256 ch, stride 264 (16B-aligned, 2-way bank)
  const int t = threadIdx.x;
  const int r0 = blockIdx.x * 64;
#pragma unroll
  for (int i = 0; i < 16; ++i) {
    int q = i * 256 + t;
    int row = q >> 6;
    int c4 = (q & 63) << 2;
    float4 v = *(const float4*)(src + (size_t)(r0 + row) * 256 + c4);
    unsigned short* p = &lds[row * 264 + c4];
    p[0] = f2bf(v.x); p[1] = f2bf(v.y); p[2] = f2bf(v.z); p[3] = f2bf(v.w);
  }
  __syncthreads();
  const int wid = t >> 6, lane = t & 63;
  const int l16 = lane & 15, lk = (lane >> 4) << 3;
  f32x4 acc[16];
#pragma unroll
  for (int i = 0; i < 16; ++i) acc[i] = (f32x4){0.f, 0.f, 0.f, 0.f};
  const unsigned short* arow = &lds[(wid * 16 + l16) * 264 + lk];
#pragma unroll
  for (int ks = 0; ks < 256; ks += 32) {
    short8 a = *(const short8*)(arow + ks);
#pragma unroll
    for (int nt = 0; nt < 16; ++nt) {
      short8 b = *(const short8*)(w + (nt * 16 + l16) * 256 + ks + lk);
      acc[nt] = __builtin_amdgcn_mfma_f32_16x16x32_bf16(a, b, acc[nt], 0, 0, 0);
    }
  }
  const int rb = r0 + wid * 16 + ((lane >> 4) << 2);
#pragma unroll
  for (int nt = 0; nt < 16; ++nt) {
    const int o = nt * 16 + l16;
    const float bo = bias[o];
#pragma unroll
    for (int j = 0; j < 4; ++j) {
      const int r = rb + j;
      const float val = acc[nt][j] + bo;
      size_t addr;
      if (MODE == 0) {
        addr = (size_t)(r >> 12) * 1048576 + (size_t)o * 4096 + (size_t)(r & 4095);
      } else if (MODE == 1) {
        const int ww = r & 63, hh = (r >> 6) & 63;
        addr = (size_t)(r >> 12) * 1048576 + (size_t)o * 4096 + (size_t)(ww * 64 + hh);
      } else {
        const int b_ = r >> 16, l_ = (r >> 12) & 15, s_ = r & 4095;
        addr = (size_t)(b_ * 16 + (o >> 4)) * 1048576 + (size_t)s_ * 256 + (size_t)(((o & 15) << 4) + l_);
      }
      dst[addr] = f2bf(val);
    }
  }
}

// attn[n][c][d] = sum_s Q[n][c][s] * K[n][d][s];  M=N=256 tiled 64x64, K=4096.
__global__ __launch_bounds__(256) void k_logits(const unsigned short* __restrict__ qb,
                                                const unsigned short* __restrict__ kb,
                                                float* __restrict__ attn) {
  const int n = blockIdx.z;
  const int c0 = blockIdx.x * 64, d0 = blockIdx.y * 64;
  const int t = threadIdx.x, wid = t >> 6, lane = t & 63;
  const int l16 = lane & 15, lk = (lane >> 4) << 3;
  const unsigned short* qrow = qb + (size_t)n * 1048576 + (size_t)(c0 + wid * 16 + l16) * 4096 + lk;
  const unsigned short* krow = kb + (size_t)n * 1048576 + (size_t)(d0 + l16) * 4096 + lk;
  f32x4 acc[4];
#pragma unroll
  for (int i = 0; i < 4; ++i) acc[i] = (f32x4){0.f, 0.f, 0.f, 0.f};
#pragma unroll 4
  for (int ks = 0; ks < 4096; ks += 32) {
    short8 a = *(const short8*)(qrow + ks);
#pragma unroll
    for (int nt = 0; nt < 4; ++nt) {
      short8 b = *(const short8*)(krow + nt * 16 * 4096 + ks);
      acc[nt] = __builtin_amdgcn_mfma_f32_16x16x32_bf16(a, b, acc[nt], 0, 0, 0);
    }
  }
  const int crow = c0 + wid * 16 + ((lane >> 4) << 2);
#pragma unroll
  for (int nt = 0; nt < 4; ++nt)
#pragma unroll
    for (int j = 0; j < 4; ++j)
      attn[(size_t)n * 65536 + (size_t)(crow + j) * 256 + (size_t)(d0 + nt * 16 + l16)] = acc[nt][j];
}

// softmax over d (256) per (n,c) row; one wave per row; write bf16 probs [n][c][d].
__global__ __launch_bounds__(256) void k_softmax(const float* __restrict__ attn,
                                                 unsigned short* __restrict__ abf) {
  const int t = threadIdx.x, wid = t >> 6, lane = t & 63;
  const int row = blockIdx.x * 4 + wid;
  const int n = row >> 8, c = row & 255;
  const float* p = attn + (size_t)n * 65536 + (size_t)c * 256;
  float v0 = p[lane], v1 = p[lane + 64], v2 = p[lane + 128], v3 = p[lane + 192];
  float m = fmaxf(fmaxf(v0, v1), fmaxf(v2, v3));
#pragma unroll
  for (int off = 32; off >= 1; off >>= 1) m = fmaxf(m, __shfl_xor(m, off, 64));
  float e0 = __expf(v0 - m), e1 = __expf(v1 - m), e2 = __expf(v2 - m), e3 = __expf(v3 - m);
  float s = e0 + e1 + e2 + e3;
#pragma unroll
  for (int off = 32; off >= 1; off >>= 1) s += __shfl_xor(s, off, 64);
  const float inv = 1.0f / s;
  unsigned short* q = abf + (size_t)n * 65536 + (size_t)c * 256;
  q[lane]       = f2bf(e0 * inv);
  q[lane + 64]  = f2bf(e1 * inv);
  q[lane + 128] = f2bf(e2 * inv);
  q[lane + 192] = f2bf(e3 * inv);
}

// out[n][s][c] = sum_d vT[n][s][d] * attn[n][c][d];  M=4096(s) x N=256(c), K=256(d).
// epilogue: out = gamma*out + x  (fp32).
__global__ __launch_bounds__(256) void k_out(const unsigned short* __restrict__ vT,
                                             const unsigned short* __restrict__ abf,
                                             const float* __restrict__ x,
                                             const float* __restrict__ gamma,
                                             float* __restrict__ out) {
  const int n = blockIdx.y;
  const int s0 = blockIdx.x * 64;
  const int t = threadIdx.x, wid = t >> 6, lane = t & 63;
  const int l16 = lane & 15, lk = (lane >> 4) << 3;
  const unsigned short* arow = vT + (size_t)n * 1048576 + (size_t)(s0 + wid * 16 + l16) * 256 + lk;
  const unsigned short* brow = abf + (size_t)n * 65536 + (size_t)l16 * 256 + lk;
  f32x4 acc[16];
#pragma unroll
  for (int i = 0; i < 16; ++i) acc[i] = (f32x4){0.f, 0.f, 0.f, 0.f};
#pragma unroll
  for (int ks = 0; ks < 256; ks += 32) {
    short8 a = *(const short8*)(arow + ks);
#pragma unroll
    for (int nt = 0; nt < 16; ++nt) {
      short8 b = *(const short8*)(brow + (size_t)nt * 16 * 256 + ks);
      acc[nt] = __builtin_amdgcn_mfma_f32_16x16x32_bf16(a, b, acc[nt], 0, 0, 0);
    }
  }
  const float g = gamma[0];
  const int sb = s0 + wid * 16 + ((lane >> 4) << 2);
#pragma unroll
  for (int nt = 0; nt < 16; ++nt) {
    const int ci = nt * 16 + l16;
#pragma unroll
    for (int j = 0; j < 4; ++j) {
      const size_t addr = ((size_t)n * 4096 + (size_t)(sb + j)) * 256 + (size_t)ci;
      out[addr] = g * acc[nt][j] + x[addr];
    }
  }
}

extern "C" void kernel_launch(void* const* d_in, const int* in_sizes, int n_in,
                              void* d_out, int out_size, void* d_ws, size_t ws_size,
                              hipStream_t stream) {
  const float* x    = (const float*)d_in[0];
  const float* prev = (const float*)d_in[1];
  const float* Wq   = (const float*)d_in[2];
  const float* bq   = (const float*)d_in[3];
  const float* Wk   = (const float*)d_in[4];
  const float* bk   = (const float*)d_in[5];
  const float* Wv   = (const float*)d_in[6];
  const float* bv   = (const float*)d_in[7];
  const float* gamma = (const float*)d_in[8];

  char* ws = (char*)d_ws;
  unsigned short* qv   = (unsigned short*)ws;                    // Q, later V^T
  unsigned short* kbuf = (unsigned short*)(ws + 67108864ULL);
  float* attn          = (float*)(ws + 134217728ULL);
  unsigned short* abf  = (unsigned short*)(ws + 142606336ULL);
  unsigned short* wbf  = (unsigned short*)(ws + 146800640ULL);

  k_convert_w<<<dim3(768), dim3(256), 0, stream>>>(Wq, Wk, Wv, wbf);
  k_qkv<0><<<dim3(2048), dim3(256), 0, stream>>>(x, wbf, bq, qv);
  k_qkv<1><<<dim3(2048), dim3(256), 0, stream>>>(prev, wbf + 65536, bk, kbuf);
  k_logits<<<dim3(4, 4, 32), dim3(256), 0, stream>>>(qv, kbuf, attn);
  // V overwrites the Q buffer; stream order guarantees k_logits consumed Q already.
  k_qkv<2><<<dim3(2048), dim3(256), 0, stream>>>(prev, wbf + 131072, bv, qv);
  k_softmax<<<dim3(2048), dim3(256), 0, stream>>>(attn, abf);
  k_out<<<dim3(64, 32), dim3(256), 0, stream>>>(qv, abf, x, gamma, (float*)d_out);
}

// Round 2
// 1181.450 us; speedup vs baseline: 1.2736x; 1.2736x over previous
//
#include <hip/hip_runtime.h>
#include <hip/hip_bf16.h>

// B=2, L=16, H=64, W=64, C=256.  n = B*L = 32, HW = 4096.
// ws layout (bytes):
//   [0, 64Mi)      : Q bf16 [n][c][s]      -> later reused as vT [n'][s][d]
//   [64Mi, 128Mi)  : K bf16 [n][d][w*64+h] -> later reused as Vbuf natural [b][c][l][s]
//   [128Mi, +8Mi)  : attn logits fp32 [n][c][d]
//   [136Mi, +4Mi)  : attn probs bf16 [n][c][d]
//   [140Mi, +384Ki]: Wq/Wk/Wv bf16

typedef short short8 __attribute__((ext_vector_type(8)));
typedef short short4v __attribute__((ext_vector_type(4)));
typedef float f32x4 __attribute__((ext_vector_type(4)));

static __device__ __forceinline__ unsigned short f2bf(float f) {
  union { __hip_bfloat16 h; unsigned short u; } cv;
  cv.h = __float2bfloat16(f);
  return cv.u;
}

__global__ __launch_bounds__(256) void k_convert_w(const float* __restrict__ wq,
                                                   const float* __restrict__ wk,
                                                   const float* __restrict__ wv,
                                                   unsigned short* __restrict__ o) {
  int i = blockIdx.x * 256 + threadIdx.x;
  const float* s = (i < 65536) ? wq : (i < 131072 ? wk : wv);
  o[i] = f2bf(s[i & 65535]);
}

// Pointwise conv GEMM: 64 rows x 256 out-ch per block, K=256.
// MODE 0: rows = 64 consecutive s within n; dst[n][o][s]              (Q)
// MODE 1: rows = fixed (n,w), h=0..63;     dst[n][o][w*64+h]          (K, contiguous in h)
// MODE 2: rows = 64 consecutive s within n; dst natural [b][c][l][s]  (V)
template <int MODE>
__global__ __launch_bounds__(256) void k_qkv(const float* __restrict__ src,
                                             const unsigned short* __restrict__ w,
                                             const float* __restrict__ bias,
                                             unsigned short* __restrict__ dst) {
  __shared__ unsigned short lds[256 * 72];  // 36864 B; first 64*264 used for input staging
  const int t = threadIdx.x;
  int n, wcol, s0;
  if (MODE == 1) {
    n = blockIdx.x >> 6; wcol = blockIdx.x & 63; s0 = 0;
  } else {
    n = blockIdx.x >> 6; wcol = 0; s0 = (blockIdx.x & 63) << 6;
  }
  // ---- input staging: 64 rows x 256 ch fp32 -> bf16, stride 264 ----
#pragma unroll
  for (int i = 0; i < 16; ++i) {
    int q = i * 256 + t;
    int row = q >> 6;
    int c4 = (q & 63) << 2;
    size_t srow = (MODE == 1) ? (size_t)(n * 4096 + row * 64 + wcol)
                              : (size_t)(n * 4096 + s0 + row);
    float4 v = *(const float4*)(src + srow * 256 + c4);
    unsigned short* p = &lds[row * 264 + c4];
    p[0] = f2bf(v.x); p[1] = f2bf(v.y); p[2] = f2bf(v.z); p[3] = f2bf(v.w);
  }
  __syncthreads();
  const int wid = t >> 6, lane = t & 63;
  const int l16 = lane & 15, lk = (lane >> 4) << 3;
  f32x4 acc[16];
#pragma unroll
  for (int i = 0; i < 16; ++i) acc[i] = (f32x4){0.f, 0.f, 0.f, 0.f};
  const unsigned short* arow = &lds[(wid * 16 + l16) * 264 + lk];
#pragma unroll
  for (int ks = 0; ks < 256; ks += 32) {
    short8 a = *(const short8*)(arow + ks);
#pragma unroll
    for (int nt = 0; nt < 16; ++nt) {
      short8 b = *(const short8*)(w + (nt * 16 + l16) * 256 + ks + lk);
      acc[nt] = __builtin_amdgcn_mfma_f32_16x16x32_bf16(a, b, acc[nt], 0, 0, 0);
    }
  }
  __syncthreads();  // all waves done reading input LDS
  // ---- bias + acc -> LDS output tile [o=256][s=64], stride 72 ----
  const int sl0 = wid * 16 + ((lane >> 4) << 2);
#pragma unroll
  for (int nt = 0; nt < 16; ++nt) {
    const int o = nt * 16 + l16;
    const float bo = bias[o];
    short4v pk;
#pragma unroll
    for (int j = 0; j < 4; ++j) pk[j] = (short)f2bf(acc[nt][j] + bo);
    *(short4v*)&lds[o * 72 + sl0] = pk;
  }
  __syncthreads();
  // ---- coalesced write-out: 8 lanes per o-row, 128 B contiguous per row ----
  const int co = t >> 3, ch = t & 7;  // co: 0..31 (o offset per pass), ch: 16B chunk
#pragma unroll
  for (int p = 0; p < 8; ++p) {
    const int o = p * 32 + co;
    short8 v = *(const short8*)&lds[o * 72 + ch * 8];
    size_t base;
    if (MODE == 0) {
      base = ((size_t)n << 20) + (size_t)o * 4096 + (size_t)(s0 + ch * 8);
    } else if (MODE == 1) {
      base = ((size_t)n << 20) + (size_t)o * 4096 + (size_t)(wcol * 64 + ch * 8);
    } else {
      const int b_ = n >> 4, l_ = n & 15;
      base = (size_t)((b_ * 256 + o) * 16 + l_) * 4096 + (size_t)(s0 + ch * 8);
    }
    *(short8*)(dst + base) = v;
  }
}

// Transpose Vbuf natural [b][c][l][s] -> vT [n'][s][d],  d = (c&15)*16 + l, n' = b*16 + c>>4.
__global__ __launch_bounds__(256) void k_vt(const unsigned short* __restrict__ vb,
                                            unsigned short* __restrict__ vt) {
  __shared__ unsigned short lds[64 * 264];
  const int t = threadIdx.x;
  const int np = blockIdx.x >> 6;
  const int s0 = (blockIdx.x & 63) << 6;
  const int b = np >> 4, chi = np & 15;
  const int d0 = (t & 127) << 1, sh = (t >> 7) << 5;  // d pair, s half
  const int c = chi * 16 + (d0 >> 4);
  const int l0 = d0 & 15;
  const unsigned short* r0p = vb + (size_t)((b * 256 + c) * 16 + l0) * 4096 + s0 + sh;
  const unsigned short* r1p = r0p + 4096;  // d0+1: same c, l0+1
#pragma unroll
  for (int i = 0; i < 4; ++i) {
    short8 a = *(const short8*)(r0p + i * 8);
    short8 bb = *(const short8*)(r1p + i * 8);
#pragma unroll
    for (int j = 0; j < 8; ++j) {
      int s = sh + i * 8 + j;
      unsigned int pk = (unsigned int)(unsigned short)a[j] |
                        ((unsigned int)(unsigned short)bb[j] << 16);
      *(unsigned int*)&lds[s * 264 + d0] = pk;
    }
  }
  __syncthreads();
  const int sl = t >> 2, ch = t & 3;
  unsigned short* outp = vt + ((size_t)np << 20) + (size_t)(s0 + sl) * 256 + ch * 64;
  const unsigned short* lp = &lds[sl * 264 + ch * 64];
#pragma unroll
  for (int i = 0; i < 8; ++i)
    *(short8*)(outp + i * 8) = *(const short8*)(lp + i * 8);
}

// attn[n][c][d] = sum_s Q[n][c][s] * K[n][d][s];  M=N=256 tiled 64x64, K=4096.
__global__ __launch_bounds__(256) void k_logits(const unsigned short* __restrict__ qb,
                                                const unsigned short* __restrict__ kb,
                                                float* __restrict__ attn) {
  const int n = blockIdx.z;
  const int c0 = blockIdx.x * 64, d0 = blockIdx.y * 64;
  const int t = threadIdx.x, wid = t >> 6, lane = t & 63;
  const int l16 = lane & 15, lk = (lane >> 4) << 3;
  const unsigned short* qrow = qb + (size_t)n * 1048576 + (size_t)(c0 + wid * 16 + l16) * 4096 + lk;
  const unsigned short* krow = kb + (size_t)n * 1048576 + (size_t)(d0 + l16) * 4096 + lk;
  f32x4 acc[4];
#pragma unroll
  for (int i = 0; i < 4; ++i) acc[i] = (f32x4){0.f, 0.f, 0.f, 0.f};
#pragma unroll 4
  for (int ks = 0; ks < 4096; ks += 32) {
    short8 a = *(const short8*)(qrow + ks);
#pragma unroll
    for (int nt = 0; nt < 4; ++nt) {
      short8 b = *(const short8*)(krow + nt * 16 * 4096 + ks);
      acc[nt] = __builtin_amdgcn_mfma_f32_16x16x32_bf16(a, b, acc[nt], 0, 0, 0);
    }
  }
  const int crow = c0 + wid * 16 + ((lane >> 4) << 2);
#pragma unroll
  for (int nt = 0; nt < 4; ++nt)
#pragma unroll
    for (int j = 0; j < 4; ++j)
      attn[(size_t)n * 65536 + (size_t)(crow + j) * 256 + (size_t)(d0 + nt * 16 + l16)] = acc[nt][j];
}

// softmax over d (256) per (n,c) row; one wave per row; write bf16 probs [n][c][d].
__global__ __launch_bounds__(256) void k_softmax(const float* __restrict__ attn,
                                                 unsigned short* __restrict__ abf) {
  const int t = threadIdx.x, wid = t >> 6, lane = t & 63;
  const int row = blockIdx.x * 4 + wid;
  const int n = row >> 8, c = row & 255;
  const float* p = attn + (size_t)n * 65536 + (size_t)c * 256;
  float v0 = p[lane], v1 = p[lane + 64], v2 = p[lane + 128], v3 = p[lane + 192];
  float m = fmaxf(fmaxf(v0, v1), fmaxf(v2, v3));
#pragma unroll
  for (int off = 32; off >= 1; off >>= 1) m = fmaxf(m, __shfl_xor(m, off, 64));
  float e0 = __expf(v0 - m), e1 = __expf(v1 - m), e2 = __expf(v2 - m), e3 = __expf(v3 - m);
  float s = e0 + e1 + e2 + e3;
#pragma unroll
  for (int off = 32; off >= 1; off >>= 1) s += __shfl_xor(s, off, 64);
  const float inv = 1.0f / s;
  unsigned short* q = abf + (size_t)n * 65536 + (size_t)c * 256;
  q[lane]       = f2bf(e0 * inv);
  q[lane + 64]  = f2bf(e1 * inv);
  q[lane + 128] = f2bf(e2 * inv);
  q[lane + 192] = f2bf(e3 * inv);
}

// out[n][s][c] = sum_d vT[n][s][d] * attn[n][c][d];  M=4096(s) x N=256(c), K=256(d).
__global__ __launch_bounds__(256) void k_out(const unsigned short* __restrict__ vT,
                                             const unsigned short* __restrict__ abf,
                                             const float* __restrict__ x,
                                             const float* __restrict__ gamma,
                                             float* __restrict__ out) {
  const int n = blockIdx.y;
  const int s0 = blockIdx.x * 64;
  const int t = threadIdx.x, wid = t >> 6, lane = t & 63;
  const int l16 = lane & 15, lk = (lane >> 4) << 3;
  const unsigned short* arow = vT + (size_t)n * 1048576 + (size_t)(s0 + wid * 16 + l16) * 256 + lk;
  const unsigned short* brow = abf + (size_t)n * 65536 + (size_t)l16 * 256 + lk;
  f32x4 acc[16];
#pragma unroll
  for (int i = 0; i < 16; ++i) acc[i] = (f32x4){0.f, 0.f, 0.f, 0.f};
#pragma unroll
  for (int ks = 0; ks < 256; ks += 32) {
    short8 a = *(const short8*)(arow + ks);
#pragma unroll
    for (int nt = 0; nt < 16; ++nt) {
      short8 b = *(const short8*)(brow + (size_t)nt * 16 * 256 + ks);
      acc[nt] = __builtin_amdgcn_mfma_f32_16x16x32_bf16(a, b, acc[nt], 0, 0, 0);
    }
  }
  const float g = gamma[0];
  const int sb = s0 + wid * 16 + ((lane >> 4) << 2);
#pragma unroll
  for (int nt = 0; nt < 16; ++nt) {
    const int ci = nt * 16 + l16;
#pragma unroll
    for (int j = 0; j < 4; ++j) {
      const size_t addr = ((size_t)n * 4096 + (size_t)(sb + j)) * 256 + (size_t)ci;
      out[addr] = g * acc[nt][j] + x[addr];
    }
  }
}

extern "C" void kernel_launch(void* const* d_in, const int* in_sizes, int n_in,
                              void* d_out, int out_size, void* d_ws, size_t ws_size,
                              hipStream_t stream) {
  const float* x    = (const float*)d_in[0];
  const float* prev = (const float*)d_in[1];
  const float* Wq   = (const float*)d_in[2];
  const float* bq   = (const float*)d_in[3];
  const float* Wk   = (const float*)d_in[4];
  const float* bk   = (const float*)d_in[5];
  const float* Wv   = (const float*)d_in[6];
  const float* bv   = (const float*)d_in[7];
  const float* gamma = (const float*)d_in[8];

  char* ws = (char*)d_ws;
  unsigned short* qv   = (unsigned short*)ws;                    // Q, later vT
  unsigned short* kbuf = (unsigned short*)(ws + 67108864ULL);    // K, later Vbuf natural
  float* attn          = (float*)(ws + 134217728ULL);
  unsigned short* abf  = (unsigned short*)(ws + 142606336ULL);
  unsigned short* wbf  = (unsigned short*)(ws + 146800640ULL);

  k_convert_w<<<dim3(768), dim3(256), 0, stream>>>(Wq, Wk, Wv, wbf);
  k_qkv<0><<<dim3(2048), dim3(256), 0, stream>>>(x, wbf, bq, qv);
  k_qkv<1><<<dim3(2048), dim3(256), 0, stream>>>(prev, wbf + 65536, bk, kbuf);
  k_logits<<<dim3(4, 4, 32), dim3(256), 0, stream>>>(qv, kbuf, attn);
  // V (natural layout) overwrites K buffer; k_logits already consumed K.
  k_qkv<2><<<dim3(2048), dim3(256), 0, stream>>>(prev, wbf + 131072, bv, kbuf);
  k_softmax<<<dim3(2048), dim3(256), 0, stream>>>(attn, abf);
  // vT overwrites Q buffer; k_logits already consumed Q.
  k_vt<<<dim3(2048), dim3(256), 0, stream>>>(kbuf, qv);
  k_out<<<dim3(64, 32), dim3(256), 0, stream>>>(qv, abf, x, gamma, (float*)d_out);
}

// Round 5
// 656.858 us; speedup vs baseline: 2.2908x; 1.7986x over previous
//
#include <hip/hip_runtime.h>
#include <hip/hip_bf16.h>

// B=2, L=16, H=64, W=64, C=256.  n = B*L = 32, HW = 4096.
// ws layout (bytes):
//   [0, 64Mi)      : Q bf16 [n][c][s]      -> later reused as vT [n'][s][d]
//   [64Mi, 128Mi)  : K bf16 [n][d][w*64+h] -> later reused as Vbuf natural [b][c][l][s]
//   [128Mi, +8Mi)  : attn logits fp32 [n][c][d]
//   [136Mi, +4Mi)  : attn probs bf16 [n][c][d]
//   [140Mi, +384Ki]: Wq/Wk/Wv bf16

typedef short short8 __attribute__((ext_vector_type(8)));
typedef short short4v __attribute__((ext_vector_type(4)));
typedef float f32x4 __attribute__((ext_vector_type(4)));

static __device__ __forceinline__ unsigned short f2bf(float f) {
  union { __hip_bfloat16 h; unsigned short u; } cv;
  cv.h = __float2bfloat16(f);
  return cv.u;
}

__global__ __launch_bounds__(256) void k_convert_w(const float* __restrict__ wq,
                                                   const float* __restrict__ wk,
                                                   const float* __restrict__ wv,
                                                   unsigned short* __restrict__ o) {
  int i = blockIdx.x * 256 + threadIdx.x;
  const float* s = (i < 65536) ? wq : (i < 131072 ? wk : wv);
  o[i] = f2bf(s[i & 65535]);
}

// Pointwise conv GEMM: 64 rows x 256 out-ch per block, K=256 in-ch.
// Weights staged in LDS in 64-wide k-chunks (coop, coalesced) so waves don't
// each re-read 128 KB from L2.
// MODE 0: rows = 64 consecutive s within n; dst[n][o][s]              (Q)
// MODE 1: rows = fixed (n,w), h=0..63;     dst[n][o][w*64+h]          (K)
// MODE 2: rows = 64 consecutive s within n; dst natural [b][c][l][s]  (V)
template <int MODE>
__global__ __launch_bounds__(256) void k_qkv(const float* __restrict__ src,
                                             const unsigned short* __restrict__ w,
                                             const float* __restrict__ bias,
                                             unsigned short* __restrict__ dst) {
  __shared__ __align__(16) unsigned short inp[64 * 264];  // 33792 B input tile
  __shared__ __align__(16) unsigned short wc[256 * 72];   // 36864 B weight chunk / out-stage
  const int t = threadIdx.x;
  int n, wcol, s0;
  if (MODE == 1) {
    n = blockIdx.x >> 6; wcol = blockIdx.x & 63; s0 = 0;
  } else {
    n = blockIdx.x >> 6; wcol = 0; s0 = (blockIdx.x & 63) << 6;
  }
  // ---- input staging: 64 rows x 256 ch fp32 -> bf16, stride 264 ----
#pragma unroll
  for (int i = 0; i < 16; ++i) {
    int q = i * 256 + t;
    int row = q >> 6;
    int c4 = (q & 63) << 2;
    size_t srow = (MODE == 1) ? (size_t)(n * 4096 + row * 64 + wcol)
                              : (size_t)(n * 4096 + s0 + row);
    float4 v = *(const float4*)(src + srow * 256 + c4);
    unsigned short* p = &inp[row * 264 + c4];
    p[0] = f2bf(v.x); p[1] = f2bf(v.y); p[2] = f2bf(v.z); p[3] = f2bf(v.w);
  }
  const int wid = t >> 6, lane = t & 63;
  const int l16 = lane & 15, lk = (lane >> 4) << 3;
  f32x4 acc[16];
#pragma unroll
  for (int i = 0; i < 16; ++i) acc[i] = (f32x4){0.f, 0.f, 0.f, 0.f};
  const unsigned short* arow = &inp[(wid * 16 + l16) * 264];
  const int wo = t >> 3, wch = t & 7;
  for (int kc = 0; kc < 4; ++kc) {
    __syncthreads();  // iter 0: input writes done; later: prev wc reads done
#pragma unroll
    for (int p = 0; p < 8; ++p) {
      const int o = p * 32 + wo;
      short8 wv = *(const short8*)(w + o * 256 + kc * 64 + wch * 8);
      *(short8*)&wc[o * 72 + wch * 8] = wv;
    }
    __syncthreads();
#pragma unroll
    for (int ks2 = 0; ks2 < 64; ks2 += 32) {
      short8 a = *(const short8*)(arow + kc * 64 + ks2 + lk);
#pragma unroll
      for (int nt = 0; nt < 16; ++nt) {
        short8 b = *(const short8*)(&wc[(nt * 16 + l16) * 72 + ks2 + lk]);
        acc[nt] = __builtin_amdgcn_mfma_f32_16x16x32_bf16(a, b, acc[nt], 0, 0, 0);
      }
    }
  }
  __syncthreads();  // done reading wc (weights)
  // ---- bias + acc -> LDS output tile [o=256][s=64], stride 72 ----
  const int sl0 = wid * 16 + ((lane >> 4) << 2);
#pragma unroll
  for (int nt = 0; nt < 16; ++nt) {
    const int o = nt * 16 + l16;
    const float bo = bias[o];
    short4v pk;
#pragma unroll
    for (int j = 0; j < 4; ++j) pk[j] = (short)f2bf(acc[nt][j] + bo);
    *(short4v*)&wc[o * 72 + sl0] = pk;
  }
  __syncthreads();
  // ---- coalesced write-out: 8 lanes per o-row, 128 B contiguous per row ----
  const int co = t >> 3, ch = t & 7;
#pragma unroll
  for (int p = 0; p < 8; ++p) {
    const int o = p * 32 + co;
    short8 v = *(const short8*)&wc[o * 72 + ch * 8];
    size_t base;
    if (MODE == 0) {
      base = ((size_t)n << 20) + (size_t)o * 4096 + (size_t)(s0 + ch * 8);
    } else if (MODE == 1) {
      base = ((size_t)n << 20) + (size_t)o * 4096 + (size_t)(wcol * 64 + ch * 8);
    } else {
      const int b_ = n >> 4, l_ = n & 15;
      base = (size_t)((b_ * 256 + o) * 16 + l_) * 4096 + (size_t)(s0 + ch * 8);
    }
    *(short8*)(dst + base) = v;
  }
}

// Transpose Vbuf natural [b][c][l][s] -> vT [n'][s][d],  d = (c&15)*16 + l, n' = b*16 + c>>4.
__global__ __launch_bounds__(256) void k_vt(const unsigned short* __restrict__ vb,
                                            unsigned short* __restrict__ vt) {
  __shared__ unsigned short lds[64 * 264];
  const int t = threadIdx.x;
  const int np = blockIdx.x >> 6;
  const int s0 = (blockIdx.x & 63) << 6;
  const int b = np >> 4, chi = np & 15;
  const int d0 = (t & 127) << 1, sh = (t >> 7) << 5;
  const int c = chi * 16 + (d0 >> 4);
  const int l0 = d0 & 15;
  const unsigned short* r0p = vb + (size_t)((b * 256 + c) * 16 + l0) * 4096 + s0 + sh;
  const unsigned short* r1p = r0p + 4096;
#pragma unroll
  for (int i = 0; i < 4; ++i) {
    short8 a = *(const short8*)(r0p + i * 8);
    short8 bb = *(const short8*)(r1p + i * 8);
#pragma unroll
    for (int j = 0; j < 8; ++j) {
      int s = sh + i * 8 + j;
      unsigned int pk = (unsigned int)(unsigned short)a[j] |
                        ((unsigned int)(unsigned short)bb[j] << 16);
      *(unsigned int*)&lds[s * 264 + d0] = pk;
    }
  }
  __syncthreads();
  const int sl = t >> 2, ch = t & 3;
  unsigned short* outp = vt + ((size_t)np << 20) + (size_t)(s0 + sl) * 256 + ch * 64;
  const unsigned short* lp = &lds[sl * 264 + ch * 64];
#pragma unroll
  for (int i = 0; i < 8; ++i)
    *(short8*)(outp + i * 8) = *(const short8*)(lp + i * 8);
}

// attn[n][c][d] = sum_s Q[n][c][s] * K[n][d][s];  M=N=256 tiled 64x64, K=4096.
__global__ __launch_bounds__(256) void k_logits(const unsigned short* __restrict__ qb,
                                                const unsigned short* __restrict__ kb,
                                                float* __restrict__ attn) {
  const int n = blockIdx.z;
  const int c0 = blockIdx.x * 64, d0 = blockIdx.y * 64;
  const int t = threadIdx.x, wid = t >> 6, lane = t & 63;
  const int l16 = lane & 15, lk = (lane >> 4) << 3;
  const unsigned short* qrow = qb + (size_t)n * 1048576 + (size_t)(c0 + wid * 16 + l16) * 4096 + lk;
  const unsigned short* krow = kb + (size_t)n * 1048576 + (size_t)(d0 + l16) * 4096 + lk;
  f32x4 acc[4];
#pragma unroll
  for (int i = 0; i < 4; ++i) acc[i] = (f32x4){0.f, 0.f, 0.f, 0.f};
#pragma unroll 4
  for (int ks = 0; ks < 4096; ks += 32) {
    short8 a = *(const short8*)(qrow + ks);
#pragma unroll
    for (int nt = 0; nt < 4; ++nt) {
      short8 b = *(const short8*)(krow + nt * 16 * 4096 + ks);
      acc[nt] = __builtin_amdgcn_mfma_f32_16x16x32_bf16(a, b, acc[nt], 0, 0, 0);
    }
  }
  const int crow = c0 + wid * 16 + ((lane >> 4) << 2);
#pragma unroll
  for (int nt = 0; nt < 4; ++nt)
#pragma unroll
    for (int j = 0; j < 4; ++j)
      attn[(size_t)n * 65536 + (size_t)(crow + j) * 256 + (size_t)(d0 + nt * 16 + l16)] = acc[nt][j];
}

// softmax over d (256) per (n,c) row; one wave per row; write bf16 probs [n][c][d].
__global__ __launch_bounds__(256) void k_softmax(const float* __restrict__ attn,
                                                 unsigned short* __restrict__ abf) {
  const int t = threadIdx.x, wid = t >> 6, lane = t & 63;
  const int row = blockIdx.x * 4 + wid;
  const int n = row >> 8, c = row & 255;
  const float* p = attn + (size_t)n * 65536 + (size_t)c * 256;
  float v0 = p[lane], v1 = p[lane + 64], v2 = p[lane + 128], v3 = p[lane + 192];
  float m = fmaxf(fmaxf(v0, v1), fmaxf(v2, v3));
#pragma unroll
  for (int off = 32; off >= 1; off >>= 1) m = fmaxf(m, __shfl_xor(m, off, 64));
  float e0 = __expf(v0 - m), e1 = __expf(v1 - m), e2 = __expf(v2 - m), e3 = __expf(v3 - m);
  float s = e0 + e1 + e2 + e3;
#pragma unroll
  for (int off = 32; off >= 1; off >>= 1) s += __shfl_xor(s, off, 64);
  const float inv = 1.0f / s;
  unsigned short* q = abf + (size_t)n * 65536 + (size_t)c * 256;
  q[lane]       = f2bf(e0 * inv);
  q[lane + 64]  = f2bf(e1 * inv);
  q[lane + 128] = f2bf(e2 * inv);
  q[lane + 192] = f2bf(e3 * inv);
}

// out[n][s][c] = sum_d vT[n][s][d] * attn[n][c][d];  per block: 64 s x 64 c, K=256.
// B-tile (attn) staged in LDS; f32 epilogue via LDS transpose, fully vectorized.
__global__ __launch_bounds__(256) void k_out(const unsigned short* __restrict__ vT,
                                             const unsigned short* __restrict__ abf,
                                             const float* __restrict__ x,
                                             const float* __restrict__ gamma,
                                             float* __restrict__ out) {
  __shared__ __align__(16) unsigned short bsm[64 * 264];  // 33792 B; reused as f32 [64][68]
  const int n = blockIdx.z;
  const int c0 = blockIdx.y * 64;
  const int s0 = blockIdx.x * 64;
  const int t = threadIdx.x, wid = t >> 6, lane = t & 63;
  const int l16 = lane & 15, lk = (lane >> 4) << 3;
  // ---- stage B-tile: abf[n][c0+row][0..255], 32 lanes cover a full 512 B row ----
  {
    const int rr = t >> 5, ch = t & 31;
#pragma unroll
    for (int i = 0; i < 8; ++i) {
      const int row = rr + i * 8;
      short8 v = *(const short8*)(abf + (size_t)n * 65536 + (size_t)(c0 + row) * 256 + ch * 8);
      *(short8*)&bsm[row * 264 + ch * 8] = v;
    }
  }
  __syncthreads();
  const unsigned short* arow = vT + (size_t)n * 1048576 + (size_t)(s0 + wid * 16 + l16) * 256 + lk;
  f32x4 acc[4];
#pragma unroll
  for (int i = 0; i < 4; ++i) acc[i] = (f32x4){0.f, 0.f, 0.f, 0.f};
#pragma unroll
  for (int ks = 0; ks < 256; ks += 32) {
    short8 a = *(const short8*)(arow + ks);
#pragma unroll
    for (int nt = 0; nt < 4; ++nt) {
      short8 b = *(const short8*)(&bsm[(nt * 16 + l16) * 264 + ks + lk]);
      acc[nt] = __builtin_amdgcn_mfma_f32_16x16x32_bf16(a, b, acc[nt], 0, 0, 0);
    }
  }
  __syncthreads();  // done reading bsm as B-tile
  float* ldsf = (float*)bsm;  // [64][68] f32 out-tile
  const int sl0 = wid * 16 + ((lane >> 4) << 2);
#pragma unroll
  for (int nt = 0; nt < 4; ++nt)
#pragma unroll
    for (int j = 0; j < 4; ++j)
      ldsf[(sl0 + j) * 68 + nt * 16 + l16] = acc[nt][j];
  __syncthreads();
  const float g = gamma[0];
  const int ch = t & 15, rr = t >> 4;
#pragma unroll
  for (int i = 0; i < 4; ++i) {
    const int row = rr + i * 16;
    f32x4 v = *(const f32x4*)&ldsf[row * 68 + ch * 4];
    const size_t addr = ((size_t)n * 4096 + (size_t)(s0 + row)) * 256 + (size_t)(c0 + ch * 4);
    float4 xv = *(const float4*)(x + addr);
    float4 ov;
    ov.x = g * v[0] + xv.x; ov.y = g * v[1] + xv.y;
    ov.z = g * v[2] + xv.z; ov.w = g * v[3] + xv.w;
    *(float4*)(out + addr) = ov;
  }
}

extern "C" void kernel_launch(void* const* d_in, const int* in_sizes, int n_in,
                              void* d_out, int out_size, void* d_ws, size_t ws_size,
                              hipStream_t stream) {
  const float* x    = (const float*)d_in[0];
  const float* prev = (const float*)d_in[1];
  const float* Wq   = (const float*)d_in[2];
  const float* bq   = (const float*)d_in[3];
  const float* Wk   = (const float*)d_in[4];
  const float* bk   = (const float*)d_in[5];
  const float* Wv   = (const float*)d_in[6];
  const float* bv   = (const float*)d_in[7];
  const float* gamma = (const float*)d_in[8];

  char* ws = (char*)d_ws;
  unsigned short* qv   = (unsigned short*)ws;                    // Q, later vT
  unsigned short* kbuf = (unsigned short*)(ws + 67108864ULL);    // K, later Vbuf natural
  float* attn          = (float*)(ws + 134217728ULL);
  unsigned short* abf  = (unsigned short*)(ws + 142606336ULL);
  unsigned short* wbf  = (unsigned short*)(ws + 146800640ULL);

  k_convert_w<<<dim3(768), dim3(256), 0, stream>>>(Wq, Wk, Wv, wbf);
  k_qkv<0><<<dim3(2048), dim3(256), 0, stream>>>(x, wbf, bq, qv);
  k_qkv<1><<<dim3(2048), dim3(256), 0, stream>>>(prev, wbf + 65536, bk, kbuf);
  k_logits<<<dim3(4, 4, 32), dim3(256), 0, stream>>>(qv, kbuf, attn);
  // V (natural layout) overwrites K buffer; k_logits already consumed K.
  k_qkv<2><<<dim3(2048), dim3(256), 0, stream>>>(prev, wbf + 131072, bv, kbuf);
  k_softmax<<<dim3(2048), dim3(256), 0, stream>>>(attn, abf);
  // vT overwrites Q buffer; k_logits already consumed Q.
  k_vt<<<dim3(2048), dim3(256), 0, stream>>>(kbuf, qv);
  k_out<<<dim3(64, 4, 32), dim3(256), 0, stream>>>(qv, abf, x, gamma, (float*)d_out);
}

// Round 6
// 574.348 us; speedup vs baseline: 2.6199x; 1.1437x over previous
//
#include <hip/hip_runtime.h>
#include <hip/hip_bf16.h>

// B=2, L=16, H=64, W=64, C=256.  n = B*L = 32, HW = 4096.
// ws layout (bytes):
//   [0, 64Mi)      : Q bf16 [n][c][s]      -> later reused as vT [n'][s][d]
//   [64Mi, 128Mi)  : K bf16 [n][d][w*64+h] -> later reused as Vbuf natural [b][c][l][s]
//   [128Mi, 144Mi) : attn logits fp32 [2(khalf)][32][256][256]
//   [144Mi, 148Mi) : attn probs bf16 [n][c][d]
//   [148Mi, +384Ki]: Wq/Wk/Wv bf16        total ~148.4 MB

typedef short short8 __attribute__((ext_vector_type(8)));
typedef short short4v __attribute__((ext_vector_type(4)));
typedef float f32x4 __attribute__((ext_vector_type(4)));

static __device__ __forceinline__ unsigned short f2bf(float f) {
  union { __hip_bfloat16 h; unsigned short u; } cv;
  cv.h = __float2bfloat16(f);
  return cv.u;
}

__global__ __launch_bounds__(256) void k_convert_w(const float* __restrict__ wq,
                                                   const float* __restrict__ wk,
                                                   const float* __restrict__ wv,
                                                   unsigned short* __restrict__ o) {
  int i = blockIdx.x * 256 + threadIdx.x;
  const float* s = (i < 65536) ? wq : (i < 131072 ? wk : wv);
  o[i] = f2bf(s[i & 65535]);
}

// Pointwise conv GEMM: 64 rows x 256 out-ch per block, K=256 in-ch. (unchanged)
template <int MODE>
__global__ __launch_bounds__(256) void k_qkv(const float* __restrict__ src,
                                             const unsigned short* __restrict__ w,
                                             const float* __restrict__ bias,
                                             unsigned short* __restrict__ dst) {
  __shared__ __align__(16) unsigned short inp[64 * 264];
  __shared__ __align__(16) unsigned short wc[256 * 72];
  const int t = threadIdx.x;
  int n, wcol, s0;
  if (MODE == 1) {
    n = blockIdx.x >> 6; wcol = blockIdx.x & 63; s0 = 0;
  } else {
    n = blockIdx.x >> 6; wcol = 0; s0 = (blockIdx.x & 63) << 6;
  }
#pragma unroll
  for (int i = 0; i < 16; ++i) {
    int q = i * 256 + t;
    int row = q >> 6;
    int c4 = (q & 63) << 2;
    size_t srow = (MODE == 1) ? (size_t)(n * 4096 + row * 64 + wcol)
                              : (size_t)(n * 4096 + s0 + row);
    float4 v = *(const float4*)(src + srow * 256 + c4);
    unsigned short* p = &inp[row * 264 + c4];
    p[0] = f2bf(v.x); p[1] = f2bf(v.y); p[2] = f2bf(v.z); p[3] = f2bf(v.w);
  }
  const int wid = t >> 6, lane = t & 63;
  const int l16 = lane & 15, lk = (lane >> 4) << 3;
  f32x4 acc[16];
#pragma unroll
  for (int i = 0; i < 16; ++i) acc[i] = (f32x4){0.f, 0.f, 0.f, 0.f};
  const unsigned short* arow = &inp[(wid * 16 + l16) * 264];
  const int wo = t >> 3, wch = t & 7;
  for (int kc = 0; kc < 4; ++kc) {
    __syncthreads();
#pragma unroll
    for (int p = 0; p < 8; ++p) {
      const int o = p * 32 + wo;
      short8 wv = *(const short8*)(w + o * 256 + kc * 64 + wch * 8);
      *(short8*)&wc[o * 72 + wch * 8] = wv;
    }
    __syncthreads();
#pragma unroll
    for (int ks2 = 0; ks2 < 64; ks2 += 32) {
      short8 a = *(const short8*)(arow + kc * 64 + ks2 + lk);
#pragma unroll
      for (int nt = 0; nt < 16; ++nt) {
        short8 b = *(const short8*)(&wc[(nt * 16 + l16) * 72 + ks2 + lk]);
        acc[nt] = __builtin_amdgcn_mfma_f32_16x16x32_bf16(a, b, acc[nt], 0, 0, 0);
      }
    }
  }
  __syncthreads();
  const int sl0 = wid * 16 + ((lane >> 4) << 2);
#pragma unroll
  for (int nt = 0; nt < 16; ++nt) {
    const int o = nt * 16 + l16;
    const float bo = bias[o];
    short4v pk;
#pragma unroll
    for (int j = 0; j < 4; ++j) pk[j] = (short)f2bf(acc[nt][j] + bo);
    *(short4v*)&wc[o * 72 + sl0] = pk;
  }
  __syncthreads();
  const int co = t >> 3, ch = t & 7;
#pragma unroll
  for (int p = 0; p < 8; ++p) {
    const int o = p * 32 + co;
    short8 v = *(const short8*)&wc[o * 72 + ch * 8];
    size_t base;
    if (MODE == 0) {
      base = ((size_t)n << 20) + (size_t)o * 4096 + (size_t)(s0 + ch * 8);
    } else if (MODE == 1) {
      base = ((size_t)n << 20) + (size_t)o * 4096 + (size_t)(wcol * 64 + ch * 8);
    } else {
      const int b_ = n >> 4, l_ = n & 15;
      base = (size_t)((b_ * 256 + o) * 16 + l_) * 4096 + (size_t)(s0 + ch * 8);
    }
    *(short8*)(dst + base) = v;
  }
}

// Transpose Vbuf natural [b][c][l][s] -> vT [n'][s][d]. (unchanged)
__global__ __launch_bounds__(256) void k_vt(const unsigned short* __restrict__ vb,
                                            unsigned short* __restrict__ vt) {
  __shared__ unsigned short lds[64 * 264];
  const int t = threadIdx.x;
  const int np = blockIdx.x >> 6;
  const int s0 = (blockIdx.x & 63) << 6;
  const int b = np >> 4, chi = np & 15;
  const int d0 = (t & 127) << 1, sh = (t >> 7) << 5;
  const int c = chi * 16 + (d0 >> 4);
  const int l0 = d0 & 15;
  const unsigned short* r0p = vb + (size_t)((b * 256 + c) * 16 + l0) * 4096 + s0 + sh;
  const unsigned short* r1p = r0p + 4096;
#pragma unroll
  for (int i = 0; i < 4; ++i) {
    short8 a = *(const short8*)(r0p + i * 8);
    short8 bb = *(const short8*)(r1p + i * 8);
#pragma unroll
    for (int j = 0; j < 8; ++j) {
      int s = sh + i * 8 + j;
      unsigned int pk = (unsigned int)(unsigned short)a[j] |
                        ((unsigned int)(unsigned short)bb[j] << 16);
      *(unsigned int*)&lds[s * 264 + d0] = pk;
    }
  }
  __syncthreads();
  const int sl = t >> 2, ch = t & 3;
  unsigned short* outp = vt + ((size_t)np << 20) + (size_t)(s0 + sl) * 256 + ch * 64;
  const unsigned short* lp = &lds[sl * 264 + ch * 64];
#pragma unroll
  for (int i = 0; i < 8; ++i)
    *(short8*)(outp + i * 8) = *(const short8*)(lp + i * 8);
}

// k_logits v2: attn[n][c][d] = sum_s Q[n][c][s]*K[n][d][s].
// Block: 64(c) x 128(d) tile, K-half of 2048 (K-split 2), BK=64, dbuf LDS via
// global_load_lds w16, XOR-chunk swizzle (chunk ^= row&7) on src + read.
// 4 waves 2x2, wave tile 32x64. grid (8 tiles, 2 khalf, 32 n) = 512 blocks.
__global__ __launch_bounds__(256) void k_logits(const unsigned short* __restrict__ qb,
                                                const unsigned short* __restrict__ kb,
                                                float* __restrict__ attn) {
  __shared__ __align__(16) unsigned short qt[2][64 * 64];
  __shared__ __align__(16) unsigned short kt[2][128 * 64];
  const int n = blockIdx.z;
  const int kh = blockIdx.y;
  const int c0 = (blockIdx.x >> 1) * 64;
  const int d0 = (blockIdx.x & 1) * 128;
  const int t = threadIdx.x, wid = t >> 6, lane = t & 63;
  const int l16 = lane & 15, l4 = lane >> 4;
  const int wr = wid >> 1, wc = wid & 1;
  const int koff0 = kh * 2048;
  const unsigned short* qg = qb + ((size_t)n << 20) + (size_t)c0 * 4096 + koff0;
  const unsigned short* kg = kb + ((size_t)n << 20) + (size_t)d0 * 4096 + koff0;
  // per-thread staging lane geometry (pos = i*4096B + wid*1024B + lane*16B)
  const int srow8 = wid * 8 + (lane >> 3);   // row within a 32-row issue group
  const int schunk = lane & 7;

  int arow[2], brow[4];
#pragma unroll
  for (int mt = 0; mt < 2; ++mt) arow[mt] = wr * 32 + mt * 16 + l16;
#pragma unroll
  for (int nt = 0; nt < 4; ++nt) brow[nt] = wc * 64 + nt * 16 + l16;

  f32x4 acc[2][4];
#pragma unroll
  for (int mt = 0; mt < 2; ++mt)
#pragma unroll
    for (int nt = 0; nt < 4; ++nt) acc[mt][nt] = (f32x4){0.f, 0.f, 0.f, 0.f};

#define STAGE(buf, kc)                                                          \
  {                                                                             \
    const int ko = (kc) * 64;                                                   \
    _Pragma("unroll")                                                           \
    for (int i = 0; i < 2; ++i) {                                               \
      const int row = i * 32 + srow8;                                           \
      const int cg = schunk ^ (row & 7);                                        \
      const unsigned short* g = qg + (size_t)row * 4096 + ko + cg * 8;          \
      unsigned short* l = &qt[buf][i * 2048 + wid * 512];                       \
      __builtin_amdgcn_global_load_lds(                                         \
          (const __attribute__((address_space(1))) unsigned int*)(const void*)g,\
          (__attribute__((address_space(3))) unsigned int*)(void*)l, 16, 0, 0); \
    }                                                                           \
    _Pragma("unroll")                                                           \
    for (int i = 0; i < 4; ++i) {                                               \
      const int row = i * 32 + srow8;                                           \
      const int cg = schunk ^ (row & 7);                                        \
      const unsigned short* g = kg + (size_t)row * 4096 + ko + cg * 8;          \
      unsigned short* l = &kt[buf][i * 2048 + wid * 512];                       \
      __builtin_amdgcn_global_load_lds(                                         \
          (const __attribute__((address_space(1))) unsigned int*)(const void*)g,\
          (__attribute__((address_space(3))) unsigned int*)(void*)l, 16, 0, 0); \
    }                                                                           \
  }

  int cur = 0;
  STAGE(0, 0);
  __syncthreads();  // implicit vmcnt(0): buf0 ready
  for (int kc = 0; kc < 32; ++kc) {
    if (kc < 31) STAGE(cur ^ 1, kc + 1);
    // compute on buf cur
    short8 bf[4][2];
#pragma unroll
    for (int nt = 0; nt < 4; ++nt)
#pragma unroll
      for (int ks = 0; ks < 2; ++ks)
        bf[nt][ks] = *(const short8*)&kt[cur][brow[nt] * 64 +
                                             (((ks * 4 + l4) ^ (brow[nt] & 7)) << 3)];
#pragma unroll
    for (int mt = 0; mt < 2; ++mt) {
      short8 a0 = *(const short8*)&qt[cur][arow[mt] * 64 + ((l4 ^ (arow[mt] & 7)) << 3)];
      short8 a1 = *(const short8*)&qt[cur][arow[mt] * 64 + (((4 + l4) ^ (arow[mt] & 7)) << 3)];
#pragma unroll
      for (int nt = 0; nt < 4; ++nt) {
        acc[mt][nt] = __builtin_amdgcn_mfma_f32_16x16x32_bf16(a0, bf[nt][0], acc[mt][nt], 0, 0, 0);
        acc[mt][nt] = __builtin_amdgcn_mfma_f32_16x16x32_bf16(a1, bf[nt][1], acc[mt][nt], 0, 0, 0);
      }
    }
    __syncthreads();  // drains prefetch (vmcnt 0) + guards buf reuse
    cur ^= 1;
  }
#undef STAGE
  float* ah = attn + (size_t)kh * 2097152 + (size_t)n * 65536;
#pragma unroll
  for (int mt = 0; mt < 2; ++mt)
#pragma unroll
    for (int nt = 0; nt < 4; ++nt) {
      const int d = d0 + wc * 64 + nt * 16 + l16;
#pragma unroll
      for (int j = 0; j < 4; ++j) {
        const int c = c0 + wr * 32 + mt * 16 + (l4 << 2) + j;
        ah[(size_t)c * 256 + d] = acc[mt][nt][j];
      }
    }
}

// softmax over d (256) per (n,c) row; logits = attn0 + attn1 (K-split halves).
__global__ __launch_bounds__(256) void k_softmax(const float* __restrict__ attn,
                                                 unsigned short* __restrict__ abf) {
  const int t = threadIdx.x, wid = t >> 6, lane = t & 63;
  const int row = blockIdx.x * 4 + wid;
  const int n = row >> 8, c = row & 255;
  const float* p0 = attn + (size_t)n * 65536 + (size_t)c * 256;
  const float* p1 = p0 + 2097152;
  float v0 = p0[lane] + p1[lane];
  float v1 = p0[lane + 64] + p1[lane + 64];
  float v2 = p0[lane + 128] + p1[lane + 128];
  float v3 = p0[lane + 192] + p1[lane + 192];
  float m = fmaxf(fmaxf(v0, v1), fmaxf(v2, v3));
#pragma unroll
  for (int off = 32; off >= 1; off >>= 1) m = fmaxf(m, __shfl_xor(m, off, 64));
  float e0 = __expf(v0 - m), e1 = __expf(v1 - m), e2 = __expf(v2 - m), e3 = __expf(v3 - m);
  float s = e0 + e1 + e2 + e3;
#pragma unroll
  for (int off = 32; off >= 1; off >>= 1) s += __shfl_xor(s, off, 64);
  const float inv = 1.0f / s;
  unsigned short* q = abf + (size_t)n * 65536 + (size_t)c * 256;
  q[lane]       = f2bf(e0 * inv);
  q[lane + 64]  = f2bf(e1 * inv);
  q[lane + 128] = f2bf(e2 * inv);
  q[lane + 192] = f2bf(e3 * inv);
}

// out[n][s][c] = sum_d vT[n][s][d] * attn[n][c][d]. (unchanged)
__global__ __launch_bounds__(256) void k_out(const unsigned short* __restrict__ vT,
                                             const unsigned short* __restrict__ abf,
                                             const float* __restrict__ x,
                                             const float* __restrict__ gamma,
                                             float* __restrict__ out) {
  __shared__ __align__(16) unsigned short bsm[64 * 264];
  const int n = blockIdx.z;
  const int c0 = blockIdx.y * 64;
  const int s0 = blockIdx.x * 64;
  const int t = threadIdx.x, wid = t >> 6, lane = t & 63;
  const int l16 = lane & 15, lk = (lane >> 4) << 3;
  {
    const int rr = t >> 5, ch = t & 31;
#pragma unroll
    for (int i = 0; i < 8; ++i) {
      const int row = rr + i * 8;
      short8 v = *(const short8*)(abf + (size_t)n * 65536 + (size_t)(c0 + row) * 256 + ch * 8);
      *(short8*)&bsm[row * 264 + ch * 8] = v;
    }
  }
  __syncthreads();
  const unsigned short* arow = vT + (size_t)n * 1048576 + (size_t)(s0 + wid * 16 + l16) * 256 + lk;
  f32x4 acc[4];
#pragma unroll
  for (int i = 0; i < 4; ++i) acc[i] = (f32x4){0.f, 0.f, 0.f, 0.f};
#pragma unroll
  for (int ks = 0; ks < 256; ks += 32) {
    short8 a = *(const short8*)(arow + ks);
#pragma unroll
    for (int nt = 0; nt < 4; ++nt) {
      short8 b = *(const short8*)(&bsm[(nt * 16 + l16) * 264 + ks + lk]);
      acc[nt] = __builtin_amdgcn_mfma_f32_16x16x32_bf16(a, b, acc[nt], 0, 0, 0);
    }
  }
  __syncthreads();
  float* ldsf = (float*)bsm;
  const int sl0 = wid * 16 + ((lane >> 4) << 2);
#pragma unroll
  for (int nt = 0; nt < 4; ++nt)
#pragma unroll
    for (int j = 0; j < 4; ++j)
      ldsf[(sl0 + j) * 68 + nt * 16 + l16] = acc[nt][j];
  __syncthreads();
  const float g = gamma[0];
  const int ch = t & 15, rr = t >> 4;
#pragma unroll
  for (int i = 0; i < 4; ++i) {
    const int row = rr + i * 16;
    f32x4 v = *(const f32x4*)&ldsf[row * 68 + ch * 4];
    const size_t addr = ((size_t)n * 4096 + (size_t)(s0 + row)) * 256 + (size_t)(c0 + ch * 4);
    float4 xv = *(const float4*)(x + addr);
    float4 ov;
    ov.x = g * v[0] + xv.x; ov.y = g * v[1] + xv.y;
    ov.z = g * v[2] + xv.z; ov.w = g * v[3] + xv.w;
    *(float4*)(out + addr) = ov;
  }
}

extern "C" void kernel_launch(void* const* d_in, const int* in_sizes, int n_in,
                              void* d_out, int out_size, void* d_ws, size_t ws_size,
                              hipStream_t stream) {
  const float* x    = (const float*)d_in[0];
  const float* prev = (const float*)d_in[1];
  const float* Wq   = (const float*)d_in[2];
  const float* bq   = (const float*)d_in[3];
  const float* Wk   = (const float*)d_in[4];
  const float* bk   = (const float*)d_in[5];
  const float* Wv   = (const float*)d_in[6];
  const float* bv   = (const float*)d_in[7];
  const float* gamma = (const float*)d_in[8];

  char* ws = (char*)d_ws;
  unsigned short* qv   = (unsigned short*)ws;                    // Q, later vT
  unsigned short* kbuf = (unsigned short*)(ws + 67108864ULL);    // K, later Vbuf natural
  float* attn          = (float*)(ws + 134217728ULL);            // [2][32][256][256] f32
  unsigned short* abf  = (unsigned short*)(ws + 150994944ULL);
  unsigned short* wbf  = (unsigned short*)(ws + 155189248ULL);

  k_convert_w<<<dim3(768), dim3(256), 0, stream>>>(Wq, Wk, Wv, wbf);
  k_qkv<0><<<dim3(2048), dim3(256), 0, stream>>>(x, wbf, bq, qv);
  k_qkv<1><<<dim3(2048), dim3(256), 0, stream>>>(prev, wbf + 65536, bk, kbuf);
  k_logits<<<dim3(8, 2, 32), dim3(256), 0, stream>>>(qv, kbuf, attn);
  // V (natural layout) overwrites K buffer; k_logits already consumed K.
  k_qkv<2><<<dim3(2048), dim3(256), 0, stream>>>(prev, wbf + 131072, bv, kbuf);
  k_softmax<<<dim3(2048), dim3(256), 0, stream>>>(attn, abf);
  // vT overwrites Q buffer; k_logits already consumed Q.
  k_vt<<<dim3(2048), dim3(256), 0, stream>>>(kbuf, qv);
  k_out<<<dim3(64, 4, 32), dim3(256), 0, stream>>>(qv, abf, x, gamma, (float*)d_out);
}

// Round 7
// 546.797 us; speedup vs baseline: 2.7519x; 1.0504x over previous
//
#include <hip/hip_runtime.h>
#include <hip/hip_bf16.h>

// B=2, L=16, H=64, W=64, C=256.  n = B*L = 32, HW = 4096.
// ws layout (bytes):
//   [0, 64Mi)      : Q bf16 [n][c][s]      -> later reused as vT [n'][s][d]
//   [64Mi, 128Mi)  : K bf16 [n][d][w*64+h] -> later reused as Vbuf natural [b][c][l][s]
//   [128Mi, 144Mi) : attn logits fp32 [2(khalf)][32][256][256]
//   [144Mi, 148Mi) : attn probs bf16 [n][c][d]
//   [148Mi, +384Ki]: Wq/Wk/Wv bf16 PRE-SWIZZLED [m][kc][o][pc][j],
//                    element = W_m[o][kc*64 + (pc^(o&7))*8 + j]

typedef short short8 __attribute__((ext_vector_type(8)));
typedef short short4v __attribute__((ext_vector_type(4)));
typedef float f32x4 __attribute__((ext_vector_type(4)));

static __device__ __forceinline__ unsigned short f2bf(float f) {
  union { __hip_bfloat16 h; unsigned short u; } cv;
  cv.h = __float2bfloat16(f);
  return cv.u;
}

// Pre-swizzled bf16 weights: out[m][kc][o][pc][j] = W_m[o][kc*64 + (pc^(o&7))*8 + j]
__global__ __launch_bounds__(256) void k_convert_w(const float* __restrict__ wq,
                                                   const float* __restrict__ wk,
                                                   const float* __restrict__ wv,
                                                   unsigned short* __restrict__ o2) {
  int i = blockIdx.x * 256 + threadIdx.x;
  int m = i >> 16;
  const float* s = (m == 0) ? wq : (m == 1 ? wk : wv);
  int r = i & 65535;
  int kc = r >> 14, o = (r >> 6) & 255, pc = (r >> 3) & 7, j = r & 7;
  int lc = pc ^ (o & 7);
  o2[i] = f2bf(s[o * 256 + kc * 64 + lc * 8 + j]);
}

// Pointwise conv GEMM v3: 64 rows(s) x 256 out-ch per block, K=256 in-ch.
// 4 waves, wave tile 64(s) x 64(o). Per kc (64-wide k-chunk):
//   - weights: 8x global_load_lds w16 from pre-swizzled global (linear->linear)
//   - input:   [64][64] bf16 chunk, XOR-chunk swizzle, 1 float4x4 + cvt per thread
//   - compute: 2 ks2 x (4 A + 4 B ds_read_b128, conflict-free) x 16 MFMA
// Epilogue: acc -> swizzled [256 o][64 s] LDS tile (reuses wc) -> coalesced stores.
// MODE 0: dst[n][o][s]; MODE 1: rows h at fixed (n,w), dst[n][o][w*64+h];
// MODE 2: dst natural [b][c][l][s].
template <int MODE>
__global__ __launch_bounds__(256, 4) void k_qkv(const float* __restrict__ src,
                                                const unsigned short* __restrict__ w,
                                                const float* __restrict__ bias,
                                                unsigned short* __restrict__ dst) {
  __shared__ __align__(16) unsigned short inp[64 * 64];  // 8 KB input k-chunk (swizzled)
  __shared__ __align__(16) unsigned short wc[256 * 64];  // 32 KB weight chunk / out-stage
  const int t = threadIdx.x;
  int n, wcol, s0;
  if (MODE == 1) {
    n = blockIdx.x >> 6; wcol = blockIdx.x & 63; s0 = 0;
  } else {
    n = blockIdx.x >> 6; wcol = 0; s0 = (blockIdx.x & 63) << 6;
  }
  const int wid = t >> 6, lane = t & 63;
  const int l16 = lane & 15, lg = lane >> 4;
  // input staging geometry: thread covers row=t>>2, 16 fp32 at qc*16
  const int irow = t >> 2, iqc = t & 3;
  const size_t isrow = (MODE == 1) ? (size_t)(n * 4096 + irow * 64 + wcol)
                                   : (size_t)(n * 4096 + s0 + irow);
  const float* isrc = src + isrow * 256 + iqc * 16;
  const unsigned short* wsrc = w + (size_t)t * 8;  // + kc*16384 per chunk

  float bo[4];
#pragma unroll
  for (int nt = 0; nt < 4; ++nt) bo[nt] = bias[wid * 64 + nt * 16 + l16];

  f32x4 acc[4][4];
#pragma unroll
  for (int mt = 0; mt < 4; ++mt)
#pragma unroll
    for (int nt = 0; nt < 4; ++nt) acc[mt][nt] = (f32x4){0.f, 0.f, 0.f, 0.f};

  for (int kc = 0; kc < 4; ++kc) {
    if (kc) __syncthreads();  // prev-chunk reads done before overwrite
    // ---- async weight staging: linear global -> linear LDS (pre-swizzled) ----
#pragma unroll
    for (int i = 0; i < 8; ++i) {
      const unsigned short* g = wsrc + kc * 16384 + i * 2048;
      unsigned short* l = &wc[i * 2048 + t * 8];
      __builtin_amdgcn_global_load_lds(
          (const __attribute__((address_space(1))) unsigned int*)(const void*)g,
          (__attribute__((address_space(3))) unsigned int*)(void*)l, 16, 0, 0);
    }
    // ---- input chunk staging: fp32 -> bf16, XOR-chunk swizzle ----
    {
      const float* p = isrc + kc * 64;
      float4 v0 = *(const float4*)(p + 0),  v1 = *(const float4*)(p + 4);
      float4 v2 = *(const float4*)(p + 8),  v3 = *(const float4*)(p + 12);
      short8 c0, c1;
      c0[0] = (short)f2bf(v0.x); c0[1] = (short)f2bf(v0.y);
      c0[2] = (short)f2bf(v0.z); c0[3] = (short)f2bf(v0.w);
      c0[4] = (short)f2bf(v1.x); c0[5] = (short)f2bf(v1.y);
      c0[6] = (short)f2bf(v1.z); c0[7] = (short)f2bf(v1.w);
      c1[0] = (short)f2bf(v2.x); c1[1] = (short)f2bf(v2.y);
      c1[2] = (short)f2bf(v2.z); c1[3] = (short)f2bf(v2.w);
      c1[4] = (short)f2bf(v3.x); c1[5] = (short)f2bf(v3.y);
      c1[6] = (short)f2bf(v3.z); c1[7] = (short)f2bf(v3.w);
      const int rx = irow & 7;
      *(short8*)&inp[irow * 64 + (((iqc * 2) ^ rx) << 3)] = c0;
      *(short8*)&inp[irow * 64 + (((iqc * 2 + 1) ^ rx) << 3)] = c1;
    }
    __syncthreads();  // drains gload_lds (vmcnt0) + input writes
    // ---- compute ----
#pragma unroll
    for (int ks2 = 0; ks2 < 2; ++ks2) {
      const int lc = ks2 * 4 + lg;
      const int px = (lc ^ (l16 & 7)) << 3;
      short8 af[4], bf[4];
#pragma unroll
      for (int mt = 0; mt < 4; ++mt)
        af[mt] = *(const short8*)&inp[(mt * 16 + l16) * 64 + px];
#pragma unroll
      for (int nt = 0; nt < 4; ++nt)
        bf[nt] = *(const short8*)&wc[(wid * 64 + nt * 16 + l16) * 64 + px];
#pragma unroll
      for (int mt = 0; mt < 4; ++mt)
#pragma unroll
        for (int nt = 0; nt < 4; ++nt)
          acc[mt][nt] = __builtin_amdgcn_mfma_f32_16x16x32_bf16(af[mt], bf[nt], acc[mt][nt], 0, 0, 0);
    }
  }
  __syncthreads();  // done reading wc as weights
  // ---- epilogue: bias + pack -> swizzled [o][64 s] tile in wc ----
#pragma unroll
  for (int mt = 0; mt < 4; ++mt) {
    const int sc = mt * 2 + (lg >> 1);      // logical s-chunk
    const int so = (lg & 1) * 4;            // offset within chunk
#pragma unroll
    for (int nt = 0; nt < 4; ++nt) {
      const int o = wid * 64 + nt * 16 + l16;
      short4v pk;
#pragma unroll
      for (int j = 0; j < 4; ++j) pk[j] = (short)f2bf(acc[mt][nt][j] + bo[nt]);
      *(short4v*)&wc[o * 64 + ((sc ^ (o & 7)) << 3) + so] = pk;
    }
  }
  __syncthreads();
  // ---- coalesced write-out ----
  const int co = t >> 3, ch = t & 7;
#pragma unroll
  for (int p = 0; p < 8; ++p) {
    const int o = p * 32 + co;
    short8 v = *(const short8*)&wc[o * 64 + ((ch ^ (o & 7)) << 3)];
    size_t base;
    if (MODE == 0) {
      base = ((size_t)n << 20) + (size_t)o * 4096 + (size_t)(s0 + ch * 8);
    } else if (MODE == 1) {
      base = ((size_t)n << 20) + (size_t)o * 4096 + (size_t)(wcol * 64 + ch * 8);
    } else {
      const int b_ = n >> 4, l_ = n & 15;
      base = (size_t)((b_ * 256 + o) * 16 + l_) * 4096 + (size_t)(s0 + ch * 8);
    }
    *(short8*)(dst + base) = v;
  }
}

// Transpose Vbuf natural [b][c][l][s] -> vT [n'][s][d]. (unchanged)
__global__ __launch_bounds__(256) void k_vt(const unsigned short* __restrict__ vb,
                                            unsigned short* __restrict__ vt) {
  __shared__ unsigned short lds[64 * 264];
  const int t = threadIdx.x;
  const int np = blockIdx.x >> 6;
  const int s0 = (blockIdx.x & 63) << 6;
  const int b = np >> 4, chi = np & 15;
  const int d0 = (t & 127) << 1, sh = (t >> 7) << 5;
  const int c = chi * 16 + (d0 >> 4);
  const int l0 = d0 & 15;
  const unsigned short* r0p = vb + (size_t)((b * 256 + c) * 16 + l0) * 4096 + s0 + sh;
  const unsigned short* r1p = r0p + 4096;
#pragma unroll
  for (int i = 0; i < 4; ++i) {
    short8 a = *(const short8*)(r0p + i * 8);
    short8 bb = *(const short8*)(r1p + i * 8);
#pragma unroll
    for (int j = 0; j < 8; ++j) {
      int s = sh + i * 8 + j;
      unsigned int pk = (unsigned int)(unsigned short)a[j] |
                        ((unsigned int)(unsigned short)bb[j] << 16);
      *(unsigned int*)&lds[s * 264 + d0] = pk;
    }
  }
  __syncthreads();
  const int sl = t >> 2, ch = t & 3;
  unsigned short* outp = vt + ((size_t)np << 20) + (size_t)(s0 + sl) * 256 + ch * 64;
  const unsigned short* lp = &lds[sl * 264 + ch * 64];
#pragma unroll
  for (int i = 0; i < 8; ++i)
    *(short8*)(outp + i * 8) = *(const short8*)(lp + i * 8);
}

// k_logits: attn[n][c][d] = sum_s Q[n][c][s]*K[n][d][s]. (unchanged from r5)
__global__ __launch_bounds__(256) void k_logits(const unsigned short* __restrict__ qb,
                                                const unsigned short* __restrict__ kb,
                                                float* __restrict__ attn) {
  __shared__ __align__(16) unsigned short qt[2][64 * 64];
  __shared__ __align__(16) unsigned short kt[2][128 * 64];
  const int n = blockIdx.z;
  const int kh = blockIdx.y;
  const int c0 = (blockIdx.x >> 1) * 64;
  const int d0 = (blockIdx.x & 1) * 128;
  const int t = threadIdx.x, wid = t >> 6, lane = t & 63;
  const int l16 = lane & 15, l4 = lane >> 4;
  const int wr = wid >> 1, wc = wid & 1;
  const int koff0 = kh * 2048;
  const unsigned short* qg = qb + ((size_t)n << 20) + (size_t)c0 * 4096 + koff0;
  const unsigned short* kg = kb + ((size_t)n << 20) + (size_t)d0 * 4096 + koff0;
  const int srow8 = wid * 8 + (lane >> 3);
  const int schunk = lane & 7;

  int arow[2], brow[4];
#pragma unroll
  for (int mt = 0; mt < 2; ++mt) arow[mt] = wr * 32 + mt * 16 + l16;
#pragma unroll
  for (int nt = 0; nt < 4; ++nt) brow[nt] = wc * 64 + nt * 16 + l16;

  f32x4 acc[2][4];
#pragma unroll
  for (int mt = 0; mt < 2; ++mt)
#pragma unroll
    for (int nt = 0; nt < 4; ++nt) acc[mt][nt] = (f32x4){0.f, 0.f, 0.f, 0.f};

#define STAGE(buf, kc)                                                          \
  {                                                                             \
    const int ko = (kc) * 64;                                                   \
    _Pragma("unroll")                                                           \
    for (int i = 0; i < 2; ++i) {                                               \
      const int row = i * 32 + srow8;                                           \
      const int cg = schunk ^ (row & 7);                                        \
      const unsigned short* g = qg + (size_t)row * 4096 + ko + cg * 8;          \
      unsigned short* l = &qt[buf][i * 2048 + wid * 512];                       \
      __builtin_amdgcn_global_load_lds(                                         \
          (const __attribute__((address_space(1))) unsigned int*)(const void*)g,\
          (__attribute__((address_space(3))) unsigned int*)(void*)l, 16, 0, 0); \
    }                                                                           \
    _Pragma("unroll")                                                           \
    for (int i = 0; i < 4; ++i) {                                               \
      const int row = i * 32 + srow8;                                           \
      const int cg = schunk ^ (row & 7);                                        \
      const unsigned short* g = kg + (size_t)row * 4096 + ko + cg * 8;          \
      unsigned short* l = &kt[buf][i * 2048 + wid * 512];                       \
      __builtin_amdgcn_global_load_lds(                                         \
          (const __attribute__((address_space(1))) unsigned int*)(const void*)g,\
          (__attribute__((address_space(3))) unsigned int*)(void*)l, 16, 0, 0); \
    }                                                                           \
  }

  int cur = 0;
  STAGE(0, 0);
  __syncthreads();
  for (int kc = 0; kc < 32; ++kc) {
    if (kc < 31) STAGE(cur ^ 1, kc + 1);
    short8 bf[4][2];
#pragma unroll
    for (int nt = 0; nt < 4; ++nt)
#pragma unroll
      for (int ks = 0; ks < 2; ++ks)
        bf[nt][ks] = *(const short8*)&kt[cur][brow[nt] * 64 +
                                             (((ks * 4 + l4) ^ (brow[nt] & 7)) << 3)];
#pragma unroll
    for (int mt = 0; mt < 2; ++mt) {
      short8 a0 = *(const short8*)&qt[cur][arow[mt] * 64 + ((l4 ^ (arow[mt] & 7)) << 3)];
      short8 a1 = *(const short8*)&qt[cur][arow[mt] * 64 + (((4 + l4) ^ (arow[mt] & 7)) << 3)];
#pragma unroll
      for (int nt = 0; nt < 4; ++nt) {
        acc[mt][nt] = __builtin_amdgcn_mfma_f32_16x16x32_bf16(a0, bf[nt][0], acc[mt][nt], 0, 0, 0);
        acc[mt][nt] = __builtin_amdgcn_mfma_f32_16x16x32_bf16(a1, bf[nt][1], acc[mt][nt], 0, 0, 0);
      }
    }
    __syncthreads();
    cur ^= 1;
  }
#undef STAGE
  float* ah = attn + (size_t)kh * 2097152 + (size_t)n * 65536;
#pragma unroll
  for (int mt = 0; mt < 2; ++mt)
#pragma unroll
    for (int nt = 0; nt < 4; ++nt) {
      const int d = d0 + wc * 64 + nt * 16 + l16;
#pragma unroll
      for (int j = 0; j < 4; ++j) {
        const int c = c0 + wr * 32 + mt * 16 + (l4 << 2) + j;
        ah[(size_t)c * 256 + d] = acc[mt][nt][j];
      }
    }
}

// softmax over d (256) per (n,c) row; logits = attn0 + attn1. (unchanged)
__global__ __launch_bounds__(256) void k_softmax(const float* __restrict__ attn,
                                                 unsigned short* __restrict__ abf) {
  const int t = threadIdx.x, wid = t >> 6, lane = t & 63;
  const int row = blockIdx.x * 4 + wid;
  const int n = row >> 8, c = row & 255;
  const float* p0 = attn + (size_t)n * 65536 + (size_t)c * 256;
  const float* p1 = p0 + 2097152;
  float v0 = p0[lane] + p1[lane];
  float v1 = p0[lane + 64] + p1[lane + 64];
  float v2 = p0[lane + 128] + p1[lane + 128];
  float v3 = p0[lane + 192] + p1[lane + 192];
  float m = fmaxf(fmaxf(v0, v1), fmaxf(v2, v3));
#pragma unroll
  for (int off = 32; off >= 1; off >>= 1) m = fmaxf(m, __shfl_xor(m, off, 64));
  float e0 = __expf(v0 - m), e1 = __expf(v1 - m), e2 = __expf(v2 - m), e3 = __expf(v3 - m);
  float s = e0 + e1 + e2 + e3;
#pragma unroll
  for (int off = 32; off >= 1; off >>= 1) s += __shfl_xor(s, off, 64);
  const float inv = 1.0f / s;
  unsigned short* q = abf + (size_t)n * 65536 + (size_t)c * 256;
  q[lane]       = f2bf(e0 * inv);
  q[lane + 64]  = f2bf(e1 * inv);
  q[lane + 128] = f2bf(e2 * inv);
  q[lane + 192] = f2bf(e3 * inv);
}

// out[n][s][c] = sum_d vT[n][s][d] * attn[n][c][d]. (unchanged)
__global__ __launch_bounds__(256) void k_out(const unsigned short* __restrict__ vT,
                                             const unsigned short* __restrict__ abf,
                                             const float* __restrict__ x,
                                             const float* __restrict__ gamma,
                                             float* __restrict__ out) {
  __shared__ __align__(16) unsigned short bsm[64 * 264];
  const int n = blockIdx.z;
  const int c0 = blockIdx.y * 64;
  const int s0 = blockIdx.x * 64;
  const int t = threadIdx.x, wid = t >> 6, lane = t & 63;
  const int l16 = lane & 15, lk = (lane >> 4) << 3;
  {
    const int rr = t >> 5, ch = t & 31;
#pragma unroll
    for (int i = 0; i < 8; ++i) {
      const int row = rr + i * 8;
      short8 v = *(const short8*)(abf + (size_t)n * 65536 + (size_t)(c0 + row) * 256 + ch * 8);
      *(short8*)&bsm[row * 264 + ch * 8] = v;
    }
  }
  __syncthreads();
  const unsigned short* arow = vT + (size_t)n * 1048576 + (size_t)(s0 + wid * 16 + l16) * 256 + lk;
  f32x4 acc[4];
#pragma unroll
  for (int i = 0; i < 4; ++i) acc[i] = (f32x4){0.f, 0.f, 0.f, 0.f};
#pragma unroll
  for (int ks = 0; ks < 256; ks += 32) {
    short8 a = *(const short8*)(arow + ks);
#pragma unroll
    for (int nt = 0; nt < 4; ++nt) {
      short8 b = *(const short8*)(&bsm[(nt * 16 + l16) * 264 + ks + lk]);
      acc[nt] = __builtin_amdgcn_mfma_f32_16x16x32_bf16(a, b, acc[nt], 0, 0, 0);
    }
  }
  __syncthreads();
  float* ldsf = (float*)bsm;
  const int sl0 = wid * 16 + ((lane >> 4) << 2);
#pragma unroll
  for (int nt = 0; nt < 4; ++nt)
#pragma unroll
    for (int j = 0; j < 4; ++j)
      ldsf[(sl0 + j) * 68 + nt * 16 + l16] = acc[nt][j];
  __syncthreads();
  const float g = gamma[0];
  const int ch = t & 15, rr = t >> 4;
#pragma unroll
  for (int i = 0; i < 4; ++i) {
    const int row = rr + i * 16;
    f32x4 v = *(const f32x4*)&ldsf[row * 68 + ch * 4];
    const size_t addr = ((size_t)n * 4096 + (size_t)(s0 + row)) * 256 + (size_t)(c0 + ch * 4);
    float4 xv = *(const float4*)(x + addr);
    float4 ov;
    ov.x = g * v[0] + xv.x; ov.y = g * v[1] + xv.y;
    ov.z = g * v[2] + xv.z; ov.w = g * v[3] + xv.w;
    *(float4*)(out + addr) = ov;
  }
}

extern "C" void kernel_launch(void* const* d_in, const int* in_sizes, int n_in,
                              void* d_out, int out_size, void* d_ws, size_t ws_size,
                              hipStream_t stream) {
  const float* x    = (const float*)d_in[0];
  const float* prev = (const float*)d_in[1];
  const float* Wq   = (const float*)d_in[2];
  const float* bq   = (const float*)d_in[3];
  const float* Wk   = (const float*)d_in[4];
  const float* bk   = (const float*)d_in[5];
  const float* Wv   = (const float*)d_in[6];
  const float* bv   = (const float*)d_in[7];
  const float* gamma = (const float*)d_in[8];

  char* ws = (char*)d_ws;
  unsigned short* qv   = (unsigned short*)ws;                    // Q, later vT
  unsigned short* kbuf = (unsigned short*)(ws + 67108864ULL);    // K, later Vbuf natural
  float* attn          = (float*)(ws + 134217728ULL);            // [2][32][256][256] f32
  unsigned short* abf  = (unsigned short*)(ws + 150994944ULL);
  unsigned short* wbf  = (unsigned short*)(ws + 155189248ULL);   // pre-swizzled weights

  k_convert_w<<<dim3(768), dim3(256), 0, stream>>>(Wq, Wk, Wv, wbf);
  k_qkv<0><<<dim3(2048), dim3(256), 0, stream>>>(x, wbf, bq, qv);
  k_qkv<1><<<dim3(2048), dim3(256), 0, stream>>>(prev, wbf + 65536, bk, kbuf);
  k_logits<<<dim3(8, 2, 32), dim3(256), 0, stream>>>(qv, kbuf, attn);
  // V (natural layout) overwrites K buffer; k_logits already consumed K.
  k_qkv<2><<<dim3(2048), dim3(256), 0, stream>>>(prev, wbf + 131072, bv, kbuf);
  k_softmax<<<dim3(2048), dim3(256), 0, stream>>>(attn, abf);
  // vT overwrites Q buffer; k_logits already consumed Q.
  k_vt<<<dim3(2048), dim3(256), 0, stream>>>(kbuf, qv);
  k_out<<<dim3(64, 4, 32), dim3(256), 0, stream>>>(qv, abf, x, gamma, (float*)d_out);
}